// Round 4
// baseline (465.867 us; speedup 1.0000x reference)
//
#include <hip/hip_runtime.h>
#include <hip/hip_bf16.h>

// Fused triplane sample + reshape-semantics MLP (32->128->128->4, ReLU),
// perm [1,2,3,0] baked. Operand-swapped MFMAs (r3). This round: LDS diet --
// the per-wave inter-layer transpose buffer is chunked to 32 channels
// (16 rows x 40 shorts, stride-40 => conflict-free at structural minimum),
// layer-2/3 accumulate chunk-by-chunk (same kc order => bitwise-identical).
// LDS 51200 -> 38912 B => 4 blocks/CU (16 waves) for latency hiding.
// All explicit waitcnt asm removed: buffer is wave-private, same-wave DS ops
// are in-order, compiler inserts tight lgkmcnt automatically.

#define C_ 32
#define HW_ (128 * 128)
#define HQS 40                /* hbq row stride in shorts (80 B, 16B-aligned) */

typedef short s8v __attribute__((ext_vector_type(8)));
typedef float f4v __attribute__((ext_vector_type(4)));
typedef unsigned int u4v __attribute__((ext_vector_type(4)));
typedef unsigned int u2v __attribute__((ext_vector_type(2)));

__device__ __attribute__((aligned(64))) unsigned short g_planes[3 * HW_ * C_]; // (3,H,W,C) bf16
__device__ __attribute__((aligned(16))) unsigned short g_w0[128 * 32];
__device__ __attribute__((aligned(16))) unsigned short g_w1[128 * 128];
__device__ __attribute__((aligned(16))) unsigned short g_w2[16 * 128];  // perm-baked, padded
__device__ __attribute__((aligned(16))) float g_b0[128];
__device__ __attribute__((aligned(16))) float g_b1[128];
__device__ __attribute__((aligned(16))) float g_b2p[16];

template <typename TO, typename FROM>
static __device__ __forceinline__ TO bitc(FROM f) {
    union { FROM a; TO b; } u; u.a = f; return u.b;
}

// MFMA operand-type shim (v8i16 vs v8bf16 builtin signature) -- proven.
template <typename V>
static __device__ __forceinline__ auto mfma_k32(V a, V b, f4v c, int)
    -> decltype(__builtin_amdgcn_mfma_f32_16x16x32_bf16(a, b, c, 0, 0, 0)) {
    return __builtin_amdgcn_mfma_f32_16x16x32_bf16(a, b, c, 0, 0, 0);
}
template <typename V>
static __device__ __forceinline__ f4v mfma_k32(V a, V b, f4v c, long) {
    typedef __bf16 b8v __attribute__((ext_vector_type(8)));
    return __builtin_amdgcn_mfma_f32_16x16x32_bf16(bitc<b8v>(a), bitc<b8v>(b), c, 0, 0, 0);
}
static __device__ __forceinline__ f4v MFMA(s8v a, s8v b, f4v c) {
    return mfma_k32(a, b, c, 0);
}

__device__ __forceinline__ unsigned short f2bf(float f) {
    union { float f; unsigned int i; } v; v.f = f;
    unsigned int r = v.i + 0x7FFFu + ((v.i >> 16) & 1u);
    return (unsigned short)(r >> 16);
}

// relu + pack 2 floats -> 1 u32 of 2 bf16 via v_cvt_pk_bf16_f32 (no builtin
// on gfx950 -- inline asm per guide T12; pure asm, scheduler may move it)
static __device__ __forceinline__ unsigned int relu_pk(float a, float b) {
    float x = a > 0.0f ? a : 0.0f;
    float y = b > 0.0f ? b : 0.0f;
    unsigned int r;
    asm("v_cvt_pk_bf16_f32 %0, %1, %2" : "=v"(r) : "v"(x), "v"(y));
    return r;
}

// ---- prep: planes (3C,H,W) fp32 -> (3,H,W,C) bf16, LDS tile transpose ------
__global__ __launch_bounds__(256) void prep_planes_k(const float* __restrict__ tp) {
    __shared__ float buf[32][65];
    const int tid = threadIdx.x;
    const int bid = blockIdx.x;          // 0..767
    const int pl  = bid >> 8;            // plane 0..2
    const int xy0 = (bid & 255) << 6;    // 64-texel chunk
#pragma unroll
    for (int i = 0; i < 8; ++i) {
        int idx = i * 256 + tid;
        int c = idx >> 6, x = idx & 63;                       // coalesced read
        buf[c][x] = tp[(pl * C_ + c) * HW_ + xy0 + x];
    }
    __syncthreads();
#pragma unroll
    for (int i = 0; i < 8; ++i) {
        int idx = i * 256 + tid;
        int x = idx >> 5, c = idx & 31;                       // coalesced write
        g_planes[(pl * HW_ + xy0 + x) * C_ + c] = f2bf(buf[c][x]);
    }
}

// ---- prep: weights/biases -> bf16; w2/b2 permuted [1,2,3,0], padded ---------
__global__ void prep_weights_k(const float* __restrict__ w0, const float* __restrict__ b0,
                               const float* __restrict__ w1, const float* __restrict__ b1,
                               const float* __restrict__ w2, const float* __restrict__ b2) {
    int i = blockIdx.x * 256 + threadIdx.x;   // 16384 threads
    if (i < 128 * 32)  g_w0[i] = f2bf(w0[i]);
    if (i < 128 * 128) g_w1[i] = f2bf(w1[i]);
    if (i < 16 * 128) {
        int n = i >> 7, k = i & 127;
        g_w2[i] = f2bf(n < 4 ? w2[((n + 1) & 3) * 128 + k] : 0.0f);
    }
    if (i < 128) { g_b0[i] = b0[i]; g_b1[i] = b1[i]; }
    if (i < 16)  g_b2p[i] = (i < 4) ? b2[(i + 1) & 3] : 0.0f;
}

// ---- bilinear sample: all 32 channels via 16B vector loads ------------------
__device__ __forceinline__ void sample_plane32(const unsigned short* __restrict__ pbase,
                                               float u, float v, float* facc) {
    float x = (u + 1.0f) * 63.5f;             // align_corners=True, W=H=128
    float y = (v + 1.0f) * 63.5f;
    float xf = floorf(x), yf = floorf(y);
    float wx = x - xf, wy = y - yf;
    int x0 = (int)xf, y0 = (int)yf;
#pragma unroll
    for (int dy = 0; dy < 2; ++dy) {
        int yi = y0 + dy;
        float wyv = dy ? wy : 1.0f - wy;
        bool vy = (yi >= 0) && (yi < 128);
        int yc = yi < 0 ? 0 : (yi > 127 ? 127 : yi);
#pragma unroll
        for (int dx = 0; dx < 2; ++dx) {
            int xi = x0 + dx;
            float wv = (dx ? wx : 1.0f - wx) * wyv;
            bool vx = (xi >= 0) && (xi < 128);
            int xc = xi < 0 ? 0 : (xi > 127 ? 127 : xi);
            wv = (vx && vy) ? wv : 0.0f;
            const u4v* cp = (const u4v*)(pbase + (yc * 128 + xc) * C_);
#pragma unroll
            for (int q = 0; q < 4; ++q) {
                u4v dw = cp[q];
#pragma unroll
                for (int jj = 0; jj < 4; ++jj) {
                    facc[q * 8 + 2 * jj]     += wv * __uint_as_float(dw[jj] << 16);
                    facc[q * 8 + 2 * jj + 1] += wv * __uint_as_float(dw[jj] & 0xFFFF0000u);
                }
            }
        }
    }
}

// ---- fused kernel -----------------------------------------------------------
__global__ __launch_bounds__(256, 4) void fused_k(const float* __restrict__ coords,
                                                  float* __restrict__ out) {
    // S[32][512] bf16 (32768 B) + 4 per-wave chunk bufs 16*HQS shorts (5120 B)
    // + bias table (1024 B) = 38912 B => 4 blocks/CU.
    __shared__ __attribute__((aligned(16))) unsigned short smem[16384 + 4 * 16 * HQS];
    __shared__ __attribute__((aligned(16))) float lds_bias[256];   // b0[128], b1[128]
    const int tid  = threadIdx.x;             // 0..255
    const int wave = tid >> 6;                // 0..3
    const int lane = tid & 63;
    const int l15  = lane & 15;
    const int quad = lane >> 4;
    const int ch8  = quad * 8;

    const int wg = blockIdx.x;                // 0..2047
    const int b  = wg >> 9;                   // batch
    const int nb = wg & 511;                  // 512-point block within batch
    const int n0 = nb << 9;

    if (tid < 128) { lds_bias[tid] = g_b0[tid]; lds_bias[128 + tid] = g_b1[tid]; }

    // ---- phase A: sample 2 points/thread, all 32 channels -> S --------------
#pragma unroll 1
    for (int pt = 0; pt < 2; ++pt) {
        const int nl = tid + pt * 256;        // n_local 0..511
        const float* cp = coords + (size_t)(b * 262144 + n0 + nl) * 3;
        const float gx = cp[0], gy = cp[1], gz = cp[2];
        float facc[32];
#pragma unroll
        for (int c = 0; c < 32; ++c) facc[c] = 0.0f;
        sample_plane32(g_planes + 0 * (HW_ * C_), gx, gy, facc);  // feat_xy
        sample_plane32(g_planes + 2 * (HW_ * C_), gx, gz, facc);  // feat_xz
        sample_plane32(g_planes + 1 * (HW_ * C_), gy, gz, facc);  // feat_yz
#pragma unroll
        for (int c = 0; c < 32; ++c)
            smem[c * 512 + nl] = f2bf(facc[c]);
    }
    __syncthreads();

    // ---- weight fragments (identical content to proven kernel) --------------
    s8v w0f[8], w1f[4][8], w2f[4];
#pragma unroll
    for (int nt = 0; nt < 8; ++nt)
        w0f[nt] = *(const s8v*)(g_w0 + (nt * 16 + l15) * 32 + ch8);
#pragma unroll
    for (int kc = 0; kc < 4; ++kc)
#pragma unroll
        for (int nt = 0; nt < 8; ++nt)
            w1f[kc][nt] = *(const s8v*)(g_w1 + (nt * 16 + l15) * 128 + kc * 32 + ch8);
#pragma unroll
    for (int kc = 0; kc < 4; ++kc)
        w2f[kc] = *(const s8v*)(g_w2 + l15 * 128 + kc * 32 + ch8);
    const f4v b2v = *(const f4v*)(g_b2p + quad * 4);   // swapped C-init, layer 3

    unsigned short* hbq = smem + 16384 + wave * (16 * HQS);  // per-wave private

    // ---- phase B: 8 tiles per wave, operand-swapped, 32-ch chunked staging --
#pragma unroll 1
    for (int i = 0; i < 8; ++i) {
        const int ci = wave * 8 + i;          // tile 0..31
        int bo = 0;
        asm volatile("" : "+v"(bo));          // opaque 0: keep bias reads in-loop
        const float* bp = lds_bias + bo;

        const s8v a = *(const s8v*)(smem + ci * 512 + l15 * 32 + ch8);

        // layer-2 accumulators, bias-initialized up front
        f4v d[8];
#pragma unroll
        for (int j = 0; j < 8; ++j)
            d[j] = *(const f4v*)(bp + 128 + j * 16 + quad * 4);

        // layer 1 -> layer 2, one 32-ch chunk (= 2 nt) at a time through hbq
#pragma unroll
        for (int kc = 0; kc < 4; ++kc) {
#pragma unroll
            for (int s = 0; s < 2; ++s) {
                const int nt = 2 * kc + s;
                const f4v bi = *(const f4v*)(bp + nt * 16 + quad * 4);
                f4v c1 = MFMA(w0f[nt], a, bi);
                u2v pk;
                pk[0] = relu_pk(c1[0], c1[1]);
                pk[1] = relu_pk(c1[2], c1[3]);
                // bytes: l15*80 + s*32 + quad*8  (8B-aligned, conflict-free)
                *(u2v*)(hbq + l15 * HQS + s * 16 + quad * 4) = pk;
            }
            const s8v a2 = *(const s8v*)(hbq + l15 * HQS + ch8);  // 16B-aligned
#pragma unroll
            for (int j = 0; j < 8; ++j)
                d[j] = MFMA(w1f[kc][j], a2, d[j]);
        }

        // layer 2 -> layer 3, same chunking (kc ascending, same accum order)
        f4v o = b2v;
#pragma unroll
        for (int kc = 0; kc < 4; ++kc) {
#pragma unroll
            for (int s = 0; s < 2; ++s) {
                const int j = 2 * kc + s;
                u2v pk;
                pk[0] = relu_pk(d[j][0], d[j][1]);
                pk[1] = relu_pk(d[j][2], d[j][3]);
                *(u2v*)(hbq + l15 * HQS + s * 16 + quad * 4) = pk;
            }
            const s8v a3 = *(const s8v*)(hbq + l15 * HQS + ch8);
            o = MFMA(w2f[kc], a3, o);
        }

        // layer 3 result: quad0 lane l15 holds comps 0..3 of its point
        if (quad == 0) {
            f4v r;
#pragma unroll
            for (int j = 0; j < 4; ++j) r[j] = o[j] > 0.0f ? o[j] : 0.0f;
            const int t = b * 16384 + ci * 512 + nb;   // global tile index
            *(f4v*)(out + (size_t)(t * 16 + l15) * 4) = r;
        }
    }
}

extern "C" void kernel_launch(void* const* d_in, const int* in_sizes, int n_in,
                              void* d_out, int out_size, void* d_ws, size_t ws_size,
                              hipStream_t stream) {
    const float* coords = (const float*)d_in[0];
    const float* tp = (const float*)d_in[1];
    const float* w0 = (const float*)d_in[2];
    const float* b0 = (const float*)d_in[3];
    const float* w1 = (const float*)d_in[4];
    const float* b1 = (const float*)d_in[5];
    const float* w2 = (const float*)d_in[6];
    const float* b2 = (const float*)d_in[7];
    float* out = (float*)d_out;               // FP32 output

    prep_planes_k<<<768, 256, 0, stream>>>(tp);
    prep_weights_k<<<64, 256, 0, stream>>>(w0, b0, w1, b1, w2, b2);
    fused_k<<<2048, 256, 0, stream>>>(coords, out);
}

// Round 5
// 214.361 us; speedup vs baseline: 2.1733x; 2.1733x over previous
//
#include <hip/hip_runtime.h>
#include <hip/hip_bf16.h>

// Fused triplane sample + reshape-semantics MLP (32->128->128->4, ReLU),
// perm [1,2,3,0] baked. Operand-swapped MFMAs (r3) + chunked 32-ch staging
// (r4, LDS 38912 B). r5: REVERT launch_bounds(256,4) -> (256). The forced
// 4-waves/EU cap (128 regs/wave) spilled the ~240-reg phase-B working set
// to scratch (FETCH 19.5MB -> 1GB, dur 155 -> 410us). Let the allocator
// size registers; occupancy comes from the LDS diet instead.

#define C_ 32
#define HW_ (128 * 128)
#define HQS 40                /* hbq row stride in shorts (80 B, 16B-aligned) */

typedef short s8v __attribute__((ext_vector_type(8)));
typedef float f4v __attribute__((ext_vector_type(4)));
typedef unsigned int u4v __attribute__((ext_vector_type(4)));
typedef unsigned int u2v __attribute__((ext_vector_type(2)));

__device__ __attribute__((aligned(64))) unsigned short g_planes[3 * HW_ * C_]; // (3,H,W,C) bf16
__device__ __attribute__((aligned(16))) unsigned short g_w0[128 * 32];
__device__ __attribute__((aligned(16))) unsigned short g_w1[128 * 128];
__device__ __attribute__((aligned(16))) unsigned short g_w2[16 * 128];  // perm-baked, padded
__device__ __attribute__((aligned(16))) float g_b0[128];
__device__ __attribute__((aligned(16))) float g_b1[128];
__device__ __attribute__((aligned(16))) float g_b2p[16];

template <typename TO, typename FROM>
static __device__ __forceinline__ TO bitc(FROM f) {
    union { FROM a; TO b; } u; u.a = f; return u.b;
}

// MFMA operand-type shim (v8i16 vs v8bf16 builtin signature) -- proven.
template <typename V>
static __device__ __forceinline__ auto mfma_k32(V a, V b, f4v c, int)
    -> decltype(__builtin_amdgcn_mfma_f32_16x16x32_bf16(a, b, c, 0, 0, 0)) {
    return __builtin_amdgcn_mfma_f32_16x16x32_bf16(a, b, c, 0, 0, 0);
}
template <typename V>
static __device__ __forceinline__ f4v mfma_k32(V a, V b, f4v c, long) {
    typedef __bf16 b8v __attribute__((ext_vector_type(8)));
    return __builtin_amdgcn_mfma_f32_16x16x32_bf16(bitc<b8v>(a), bitc<b8v>(b), c, 0, 0, 0);
}
static __device__ __forceinline__ f4v MFMA(s8v a, s8v b, f4v c) {
    return mfma_k32(a, b, c, 0);
}

__device__ __forceinline__ unsigned short f2bf(float f) {
    union { float f; unsigned int i; } v; v.f = f;
    unsigned int r = v.i + 0x7FFFu + ((v.i >> 16) & 1u);
    return (unsigned short)(r >> 16);
}

// relu + pack 2 floats -> 1 u32 of 2 bf16 via v_cvt_pk_bf16_f32 (no builtin
// on gfx950 -- inline asm per guide T12; pure asm, scheduler may move it)
static __device__ __forceinline__ unsigned int relu_pk(float a, float b) {
    float x = a > 0.0f ? a : 0.0f;
    float y = b > 0.0f ? b : 0.0f;
    unsigned int r;
    asm("v_cvt_pk_bf16_f32 %0, %1, %2" : "=v"(r) : "v"(x), "v"(y));
    return r;
}

// ---- prep: planes (3C,H,W) fp32 -> (3,H,W,C) bf16, LDS tile transpose ------
__global__ __launch_bounds__(256) void prep_planes_k(const float* __restrict__ tp) {
    __shared__ float buf[32][65];
    const int tid = threadIdx.x;
    const int bid = blockIdx.x;          // 0..767
    const int pl  = bid >> 8;            // plane 0..2
    const int xy0 = (bid & 255) << 6;    // 64-texel chunk
#pragma unroll
    for (int i = 0; i < 8; ++i) {
        int idx = i * 256 + tid;
        int c = idx >> 6, x = idx & 63;                       // coalesced read
        buf[c][x] = tp[(pl * C_ + c) * HW_ + xy0 + x];
    }
    __syncthreads();
#pragma unroll
    for (int i = 0; i < 8; ++i) {
        int idx = i * 256 + tid;
        int x = idx >> 5, c = idx & 31;                       // coalesced write
        g_planes[(pl * HW_ + xy0 + x) * C_ + c] = f2bf(buf[c][x]);
    }
}

// ---- prep: weights/biases -> bf16; w2/b2 permuted [1,2,3,0], padded ---------
__global__ void prep_weights_k(const float* __restrict__ w0, const float* __restrict__ b0,
                               const float* __restrict__ w1, const float* __restrict__ b1,
                               const float* __restrict__ w2, const float* __restrict__ b2) {
    int i = blockIdx.x * 256 + threadIdx.x;   // 16384 threads
    if (i < 128 * 32)  g_w0[i] = f2bf(w0[i]);
    if (i < 128 * 128) g_w1[i] = f2bf(w1[i]);
    if (i < 16 * 128) {
        int n = i >> 7, k = i & 127;
        g_w2[i] = f2bf(n < 4 ? w2[((n + 1) & 3) * 128 + k] : 0.0f);
    }
    if (i < 128) { g_b0[i] = b0[i]; g_b1[i] = b1[i]; }
    if (i < 16)  g_b2p[i] = (i < 4) ? b2[(i + 1) & 3] : 0.0f;
}

// ---- bilinear sample: all 32 channels via 16B vector loads ------------------
__device__ __forceinline__ void sample_plane32(const unsigned short* __restrict__ pbase,
                                               float u, float v, float* facc) {
    float x = (u + 1.0f) * 63.5f;             // align_corners=True, W=H=128
    float y = (v + 1.0f) * 63.5f;
    float xf = floorf(x), yf = floorf(y);
    float wx = x - xf, wy = y - yf;
    int x0 = (int)xf, y0 = (int)yf;
#pragma unroll
    for (int dy = 0; dy < 2; ++dy) {
        int yi = y0 + dy;
        float wyv = dy ? wy : 1.0f - wy;
        bool vy = (yi >= 0) && (yi < 128);
        int yc = yi < 0 ? 0 : (yi > 127 ? 127 : yi);
#pragma unroll
        for (int dx = 0; dx < 2; ++dx) {
            int xi = x0 + dx;
            float wv = (dx ? wx : 1.0f - wx) * wyv;
            bool vx = (xi >= 0) && (xi < 128);
            int xc = xi < 0 ? 0 : (xi > 127 ? 127 : xi);
            wv = (vx && vy) ? wv : 0.0f;
            const u4v* cp = (const u4v*)(pbase + (yc * 128 + xc) * C_);
#pragma unroll
            for (int q = 0; q < 4; ++q) {
                u4v dw = cp[q];
#pragma unroll
                for (int jj = 0; jj < 4; ++jj) {
                    facc[q * 8 + 2 * jj]     += wv * __uint_as_float(dw[jj] << 16);
                    facc[q * 8 + 2 * jj + 1] += wv * __uint_as_float(dw[jj] & 0xFFFF0000u);
                }
            }
        }
    }
}

// ---- fused kernel -----------------------------------------------------------
__global__ __launch_bounds__(256) void fused_k(const float* __restrict__ coords,
                                               float* __restrict__ out) {
    // S[32][512] bf16 (32768 B) + 4 per-wave chunk bufs 16*HQS shorts (5120 B)
    // + bias table (1024 B) = 38912 B => 4 blocks/CU by LDS.
    __shared__ __attribute__((aligned(16))) unsigned short smem[16384 + 4 * 16 * HQS];
    __shared__ __attribute__((aligned(16))) float lds_bias[256];   // b0[128], b1[128]
    const int tid  = threadIdx.x;             // 0..255
    const int wave = tid >> 6;                // 0..3
    const int lane = tid & 63;
    const int l15  = lane & 15;
    const int quad = lane >> 4;
    const int ch8  = quad * 8;

    const int wg = blockIdx.x;                // 0..2047
    const int b  = wg >> 9;                   // batch
    const int nb = wg & 511;                  // 512-point block within batch
    const int n0 = nb << 9;

    if (tid < 128) { lds_bias[tid] = g_b0[tid]; lds_bias[128 + tid] = g_b1[tid]; }

    // ---- phase A: sample 2 points/thread, all 32 channels -> S --------------
#pragma unroll 1
    for (int pt = 0; pt < 2; ++pt) {
        const int nl = tid + pt * 256;        // n_local 0..511
        const float* cp = coords + (size_t)(b * 262144 + n0 + nl) * 3;
        const float gx = cp[0], gy = cp[1], gz = cp[2];
        float facc[32];
#pragma unroll
        for (int c = 0; c < 32; ++c) facc[c] = 0.0f;
        sample_plane32(g_planes + 0 * (HW_ * C_), gx, gy, facc);  // feat_xy
        sample_plane32(g_planes + 2 * (HW_ * C_), gx, gz, facc);  // feat_xz
        sample_plane32(g_planes + 1 * (HW_ * C_), gy, gz, facc);  // feat_yz
#pragma unroll
        for (int c = 0; c < 32; ++c)
            smem[c * 512 + nl] = f2bf(facc[c]);
    }
    __syncthreads();

    // ---- weight fragments (identical content to proven kernel) --------------
    s8v w0f[8], w1f[4][8], w2f[4];
#pragma unroll
    for (int nt = 0; nt < 8; ++nt)
        w0f[nt] = *(const s8v*)(g_w0 + (nt * 16 + l15) * 32 + ch8);
#pragma unroll
    for (int kc = 0; kc < 4; ++kc)
#pragma unroll
        for (int nt = 0; nt < 8; ++nt)
            w1f[kc][nt] = *(const s8v*)(g_w1 + (nt * 16 + l15) * 128 + kc * 32 + ch8);
#pragma unroll
    for (int kc = 0; kc < 4; ++kc)
        w2f[kc] = *(const s8v*)(g_w2 + l15 * 128 + kc * 32 + ch8);
    const f4v b2v = *(const f4v*)(g_b2p + quad * 4);   // swapped C-init, layer 3

    unsigned short* hbq = smem + 16384 + wave * (16 * HQS);  // per-wave private

    // ---- phase B: 8 tiles per wave, operand-swapped, 32-ch chunked staging --
#pragma unroll 1
    for (int i = 0; i < 8; ++i) {
        const int ci = wave * 8 + i;          // tile 0..31
        int bo = 0;
        asm volatile("" : "+v"(bo));          // opaque 0: keep bias reads in-loop
        const float* bp = lds_bias + bo;

        const s8v a = *(const s8v*)(smem + ci * 512 + l15 * 32 + ch8);

        // layer-2 accumulators, bias-initialized up front
        f4v d[8];
#pragma unroll
        for (int j = 0; j < 8; ++j)
            d[j] = *(const f4v*)(bp + 128 + j * 16 + quad * 4);

        // layer 1 -> layer 2, one 32-ch chunk (= 2 nt) at a time through hbq
#pragma unroll
        for (int kc = 0; kc < 4; ++kc) {
#pragma unroll
            for (int s = 0; s < 2; ++s) {
                const int nt = 2 * kc + s;
                const f4v bi = *(const f4v*)(bp + nt * 16 + quad * 4);
                f4v c1 = MFMA(w0f[nt], a, bi);
                u2v pk;
                pk[0] = relu_pk(c1[0], c1[1]);
                pk[1] = relu_pk(c1[2], c1[3]);
                // bytes: l15*80 + s*32 + quad*8  (8B-aligned, conflict-free)
                *(u2v*)(hbq + l15 * HQS + s * 16 + quad * 4) = pk;
            }
            const s8v a2 = *(const s8v*)(hbq + l15 * HQS + ch8);  // 16B-aligned
#pragma unroll
            for (int j = 0; j < 8; ++j)
                d[j] = MFMA(w1f[kc][j], a2, d[j]);
        }

        // layer 2 -> layer 3, same chunking (kc ascending, same accum order)
        f4v o = b2v;
#pragma unroll
        for (int kc = 0; kc < 4; ++kc) {
#pragma unroll
            for (int s = 0; s < 2; ++s) {
                const int j = 2 * kc + s;
                u2v pk;
                pk[0] = relu_pk(d[j][0], d[j][1]);
                pk[1] = relu_pk(d[j][2], d[j][3]);
                *(u2v*)(hbq + l15 * HQS + s * 16 + quad * 4) = pk;
            }
            const s8v a3 = *(const s8v*)(hbq + l15 * HQS + ch8);
            o = MFMA(w2f[kc], a3, o);
        }

        // layer 3 result: quad0 lane l15 holds comps 0..3 of its point
        if (quad == 0) {
            f4v r;
#pragma unroll
            for (int j = 0; j < 4; ++j) r[j] = o[j] > 0.0f ? o[j] : 0.0f;
            const int t = b * 16384 + ci * 512 + nb;   // global tile index
            *(f4v*)(out + (size_t)(t * 16 + l15) * 4) = r;
        }
    }
}

extern "C" void kernel_launch(void* const* d_in, const int* in_sizes, int n_in,
                              void* d_out, int out_size, void* d_ws, size_t ws_size,
                              hipStream_t stream) {
    const float* coords = (const float*)d_in[0];
    const float* tp = (const float*)d_in[1];
    const float* w0 = (const float*)d_in[2];
    const float* b0 = (const float*)d_in[3];
    const float* w1 = (const float*)d_in[4];
    const float* b1 = (const float*)d_in[5];
    const float* w2 = (const float*)d_in[6];
    const float* b2 = (const float*)d_in[7];
    float* out = (float*)d_out;               // FP32 output

    prep_planes_k<<<768, 256, 0, stream>>>(tp);
    prep_weights_k<<<64, 256, 0, stream>>>(w0, b0, w1, b1, w2, b2);
    fused_k<<<2048, 256, 0, stream>>>(coords, out);
}

// Round 6
// 206.096 us; speedup vs baseline: 2.2604x; 1.0401x over previous
//
#include <hip/hip_runtime.h>
#include <hip/hip_bf16.h>

// Fused triplane sample + reshape-semantics MLP (32->128->128->4, ReLU),
// perm [1,2,3,0] baked. Operand-swapped MFMAs (r3) + chunked 32-ch staging
// (r4). r6: phase-A gather COALESCING remap -- lane = point*4 + quarter, so
// 4 consecutive lanes load the 4 contiguous 16B quarters of one 64B texel:
// wave-gathers touch 16 distinct cache lines instead of 64 (4x fewer TCP
// request cycles; phase A was request-throughput bound at ~82us). facc
// shrinks 32->8 floats. S-writes get an XOR swizzle (nl ^ (qa<<4)) to stay
// bank-conflict-free with only 16 distinct nl per wave; the read side's
// matching XOR is the per-thread constant (wave<<4) since ci>>3 == wave.
// Values bitwise-identical to r5 (same math, same order).

#define C_ 32
#define HW_ (128 * 128)
#define HQS 40                /* hbq row stride in shorts (80 B, 16B-aligned) */

typedef short s8v __attribute__((ext_vector_type(8)));
typedef float f4v __attribute__((ext_vector_type(4)));
typedef unsigned int u4v __attribute__((ext_vector_type(4)));
typedef unsigned int u2v __attribute__((ext_vector_type(2)));

__device__ __attribute__((aligned(64))) unsigned short g_planes[3 * HW_ * C_]; // (3,H,W,C) bf16
__device__ __attribute__((aligned(16))) unsigned short g_w0[128 * 32];
__device__ __attribute__((aligned(16))) unsigned short g_w1[128 * 128];
__device__ __attribute__((aligned(16))) unsigned short g_w2[16 * 128];  // perm-baked, padded
__device__ __attribute__((aligned(16))) float g_b0[128];
__device__ __attribute__((aligned(16))) float g_b1[128];
__device__ __attribute__((aligned(16))) float g_b2p[16];

template <typename TO, typename FROM>
static __device__ __forceinline__ TO bitc(FROM f) {
    union { FROM a; TO b; } u; u.a = f; return u.b;
}

// MFMA operand-type shim (v8i16 vs v8bf16 builtin signature) -- proven.
template <typename V>
static __device__ __forceinline__ auto mfma_k32(V a, V b, f4v c, int)
    -> decltype(__builtin_amdgcn_mfma_f32_16x16x32_bf16(a, b, c, 0, 0, 0)) {
    return __builtin_amdgcn_mfma_f32_16x16x32_bf16(a, b, c, 0, 0, 0);
}
template <typename V>
static __device__ __forceinline__ f4v mfma_k32(V a, V b, f4v c, long) {
    typedef __bf16 b8v __attribute__((ext_vector_type(8)));
    return __builtin_amdgcn_mfma_f32_16x16x32_bf16(bitc<b8v>(a), bitc<b8v>(b), c, 0, 0, 0);
}
static __device__ __forceinline__ f4v MFMA(s8v a, s8v b, f4v c) {
    return mfma_k32(a, b, c, 0);
}

__device__ __forceinline__ unsigned short f2bf(float f) {
    union { float f; unsigned int i; } v; v.f = f;
    unsigned int r = v.i + 0x7FFFu + ((v.i >> 16) & 1u);
    return (unsigned short)(r >> 16);
}

// relu + pack 2 floats -> 1 u32 of 2 bf16 via v_cvt_pk_bf16_f32 (no builtin
// on gfx950 -- inline asm per guide T12)
static __device__ __forceinline__ unsigned int relu_pk(float a, float b) {
    float x = a > 0.0f ? a : 0.0f;
    float y = b > 0.0f ? b : 0.0f;
    unsigned int r;
    asm("v_cvt_pk_bf16_f32 %0, %1, %2" : "=v"(r) : "v"(x), "v"(y));
    return r;
}

// ---- prep: planes (3C,H,W) fp32 -> (3,H,W,C) bf16, LDS tile transpose ------
__global__ __launch_bounds__(256) void prep_planes_k(const float* __restrict__ tp) {
    __shared__ float buf[32][65];
    const int tid = threadIdx.x;
    const int bid = blockIdx.x;          // 0..767
    const int pl  = bid >> 8;            // plane 0..2
    const int xy0 = (bid & 255) << 6;    // 64-texel chunk
#pragma unroll
    for (int i = 0; i < 8; ++i) {
        int idx = i * 256 + tid;
        int c = idx >> 6, x = idx & 63;                       // coalesced read
        buf[c][x] = tp[(pl * C_ + c) * HW_ + xy0 + x];
    }
    __syncthreads();
#pragma unroll
    for (int i = 0; i < 8; ++i) {
        int idx = i * 256 + tid;
        int x = idx >> 5, c = idx & 31;                       // coalesced write
        g_planes[(pl * HW_ + xy0 + x) * C_ + c] = f2bf(buf[c][x]);
    }
}

// ---- prep: weights/biases -> bf16; w2/b2 permuted [1,2,3,0], padded ---------
__global__ void prep_weights_k(const float* __restrict__ w0, const float* __restrict__ b0,
                               const float* __restrict__ w1, const float* __restrict__ b1,
                               const float* __restrict__ w2, const float* __restrict__ b2) {
    int i = blockIdx.x * 256 + threadIdx.x;   // 16384 threads
    if (i < 128 * 32)  g_w0[i] = f2bf(w0[i]);
    if (i < 128 * 128) g_w1[i] = f2bf(w1[i]);
    if (i < 16 * 128) {
        int n = i >> 7, k = i & 127;
        g_w2[i] = f2bf(n < 4 ? w2[((n + 1) & 3) * 128 + k] : 0.0f);
    }
    if (i < 128) { g_b0[i] = b0[i]; g_b1[i] = b1[i]; }
    if (i < 16)  g_b2p[i] = (i < 4) ? b2[(i + 1) & 3] : 0.0f;
}

// ---- bilinear sample: 8 channels (one 16B quarter) of one point ------------
__device__ __forceinline__ void sample_plane8(const unsigned short* __restrict__ pbase,
                                              float u, float v, float* facc) {
    float x = (u + 1.0f) * 63.5f;             // align_corners=True, W=H=128
    float y = (v + 1.0f) * 63.5f;
    float xf = floorf(x), yf = floorf(y);
    float wx = x - xf, wy = y - yf;
    int x0 = (int)xf, y0 = (int)yf;
#pragma unroll
    for (int dy = 0; dy < 2; ++dy) {
        int yi = y0 + dy;
        float wyv = dy ? wy : 1.0f - wy;
        bool vy = (yi >= 0) && (yi < 128);
        int yc = yi < 0 ? 0 : (yi > 127 ? 127 : yi);
#pragma unroll
        for (int dx = 0; dx < 2; ++dx) {
            int xi = x0 + dx;
            float wv = (dx ? wx : 1.0f - wx) * wyv;
            bool vx = (xi >= 0) && (xi < 128);
            int xc = xi < 0 ? 0 : (xi > 127 ? 127 : xi);
            wv = (vx && vy) ? wv : 0.0f;
            const u4v dw = *(const u4v*)(pbase + (yc * 128 + xc) * C_);
#pragma unroll
            for (int jj = 0; jj < 4; ++jj) {
                facc[2 * jj]     += wv * __uint_as_float(dw[jj] << 16);
                facc[2 * jj + 1] += wv * __uint_as_float(dw[jj] & 0xFFFF0000u);
            }
        }
    }
}

// ---- fused kernel -----------------------------------------------------------
__global__ __launch_bounds__(256) void fused_k(const float* __restrict__ coords,
                                               float* __restrict__ out) {
    // S[32][512] bf16 (32768 B) + 4 per-wave chunk bufs 16*HQS shorts (5120 B)
    // + bias table (1024 B) = 38912 B.
    __shared__ __attribute__((aligned(16))) unsigned short smem[16384 + 4 * 16 * HQS];
    __shared__ __attribute__((aligned(16))) float lds_bias[256];   // b0[128], b1[128]
    const int tid  = threadIdx.x;             // 0..255
    const int wave = tid >> 6;                // 0..3
    const int lane = tid & 63;
    const int l15  = lane & 15;
    const int quad = lane >> 4;
    const int ch8  = quad * 8;

    const int wg = blockIdx.x;                // 0..2047
    const int b  = wg >> 9;                   // batch
    const int nb = wg & 511;                  // 512-point block within batch
    const int n0 = nb << 9;

    if (tid < 128) { lds_bias[tid] = g_b0[tid]; lds_bias[128 + tid] = g_b1[tid]; }

    // ---- phase A: coalesced gather remap ------------------------------------
    // lane = p15*4 + qa: 4 consecutive lanes load the 4 contiguous 16B
    // quarters of one texel => 16 distinct lines per wave-gather (was 64).
    {
        const int qa  = lane & 3;             // channel quarter 0..3
        const int p15 = lane >> 2;            // point-within-group 0..15
        const unsigned short* pb0 = g_planes + 0 * (HW_ * C_) + qa * 8;
        const unsigned short* pb1 = g_planes + 1 * (HW_ * C_) + qa * 8;
        const unsigned short* pb2 = g_planes + 2 * (HW_ * C_) + qa * 8;
#pragma unroll 1
        for (int s = 0; s < 8; ++s) {
            const int nl = s * 64 + wave * 16 + p15;   // 0..511
            const float* cp = coords + (size_t)(b * 262144 + n0 + nl) * 3;
            const float gx = cp[0], gy = cp[1], gz = cp[2];
            float facc[8];
#pragma unroll
            for (int j = 0; j < 8; ++j) facc[j] = 0.0f;
            sample_plane8(pb0, gx, gy, facc);  // feat_xy
            sample_plane8(pb2, gx, gz, facc);  // feat_xz
            sample_plane8(pb1, gy, gz, facc);  // feat_yz
            // XOR swizzle keeps writes conflict-free (32 banks across lanes)
            const int nlx = nl ^ (qa << 4);
#pragma unroll
            for (int j = 0; j < 8; ++j)
                smem[(qa * 8 + j) * 512 + nlx] = f2bf(facc[j]);
        }
    }
    __syncthreads();

    // ---- weight fragments (identical content to proven kernel) --------------
    s8v w0f[8], w1f[4][8], w2f[4];
#pragma unroll
    for (int nt = 0; nt < 8; ++nt)
        w0f[nt] = *(const s8v*)(g_w0 + (nt * 16 + l15) * 32 + ch8);
#pragma unroll
    for (int kc = 0; kc < 4; ++kc)
#pragma unroll
        for (int nt = 0; nt < 8; ++nt)
            w1f[kc][nt] = *(const s8v*)(g_w1 + (nt * 16 + l15) * 128 + kc * 32 + ch8);
#pragma unroll
    for (int kc = 0; kc < 4; ++kc)
        w2f[kc] = *(const s8v*)(g_w2 + l15 * 128 + kc * 32 + ch8);
    const f4v b2v = *(const f4v*)(g_b2p + quad * 4);   // swapped C-init, layer 3

    unsigned short* hbq = smem + 16384 + wave * (16 * HQS);  // per-wave private
    const int xw = wave << 4;                 // read-side un-swizzle (ci>>3==wave)

    // ---- phase B: 8 tiles per wave, operand-swapped, 32-ch chunked staging --
#pragma unroll 1
    for (int i = 0; i < 8; ++i) {
        const int ci = wave * 8 + i;          // tile 0..31
        int bo = 0;
        asm volatile("" : "+v"(bo));          // opaque 0: keep bias reads in-loop
        const float* bp = lds_bias + bo;

        const s8v a = *(const s8v*)(smem + ci * 512 + ((l15 * 32 + ch8) ^ xw));

        // layer-2 accumulators, bias-initialized up front
        f4v d[8];
#pragma unroll
        for (int j = 0; j < 8; ++j)
            d[j] = *(const f4v*)(bp + 128 + j * 16 + quad * 4);

        // layer 1 -> layer 2, one 32-ch chunk (= 2 nt) at a time through hbq
#pragma unroll
        for (int kc = 0; kc < 4; ++kc) {
#pragma unroll
            for (int s = 0; s < 2; ++s) {
                const int nt = 2 * kc + s;
                const f4v bi = *(const f4v*)(bp + nt * 16 + quad * 4);
                f4v c1 = MFMA(w0f[nt], a, bi);
                u2v pk;
                pk[0] = relu_pk(c1[0], c1[1]);
                pk[1] = relu_pk(c1[2], c1[3]);
                // bytes: l15*80 + s*32 + quad*8  (8B-aligned, conflict-free)
                *(u2v*)(hbq + l15 * HQS + s * 16 + quad * 4) = pk;
            }
            const s8v a2 = *(const s8v*)(hbq + l15 * HQS + ch8);  // 16B-aligned
#pragma unroll
            for (int j = 0; j < 8; ++j)
                d[j] = MFMA(w1f[kc][j], a2, d[j]);
        }

        // layer 2 -> layer 3, same chunking (kc ascending, same accum order)
        f4v o = b2v;
#pragma unroll
        for (int kc = 0; kc < 4; ++kc) {
#pragma unroll
            for (int s = 0; s < 2; ++s) {
                const int j = 2 * kc + s;
                u2v pk;
                pk[0] = relu_pk(d[j][0], d[j][1]);
                pk[1] = relu_pk(d[j][2], d[j][3]);
                *(u2v*)(hbq + l15 * HQS + s * 16 + quad * 4) = pk;
            }
            const s8v a3 = *(const s8v*)(hbq + l15 * HQS + ch8);
            o = MFMA(w2f[kc], a3, o);
        }

        // layer 3 result: quad0 lane l15 holds comps 0..3 of its point
        if (quad == 0) {
            f4v r;
#pragma unroll
            for (int j = 0; j < 4; ++j) r[j] = o[j] > 0.0f ? o[j] : 0.0f;
            const int t = b * 16384 + ci * 512 + nb;   // global tile index
            *(f4v*)(out + (size_t)(t * 16 + l15) * 4) = r;
        }
    }
}

extern "C" void kernel_launch(void* const* d_in, const int* in_sizes, int n_in,
                              void* d_out, int out_size, void* d_ws, size_t ws_size,
                              hipStream_t stream) {
    const float* coords = (const float*)d_in[0];
    const float* tp = (const float*)d_in[1];
    const float* w0 = (const float*)d_in[2];
    const float* b0 = (const float*)d_in[3];
    const float* w1 = (const float*)d_in[4];
    const float* b1 = (const float*)d_in[5];
    const float* w2 = (const float*)d_in[6];
    const float* b2 = (const float*)d_in[7];
    float* out = (float*)d_out;               // FP32 output

    prep_planes_k<<<768, 256, 0, stream>>>(tp);
    prep_weights_k<<<64, 256, 0, stream>>>(w0, b0, w1, b1, w2, b2);
    fused_k<<<2048, 256, 0, stream>>>(coords, out);
}

// Round 7
// 202.426 us; speedup vs baseline: 2.3014x; 1.0181x over previous
//
#include <hip/hip_runtime.h>
#include <hip/hip_bf16.h>

// Fused triplane sample + reshape-semantics MLP (32->128->128->4, ReLU),
// perm [1,2,3,0] baked. Operand-swapped MFMAs (r3) + chunked 32-ch staging
// (r4) + coalesced 4-lane/texel gather (r6). r7: phase-A VALU diet --
// (a) per-AXIS interp math computed once (3 axes, not 6 plane-redundant),
// (b) clamp-free corners: base index min'ed to 126 once per axis (inputs
//     guaranteed in [-1,1]; x==127 edge reproduces reference via exact-zero
//     weights), deleting all per-corner clamp/validity cndmask chains,
// (c) 2 row pointers per plane, +64B corner folds into load imm offset,
// (d) S-writes use v_cvt_pk_bf16_f32 (proven == f2bf in r3) -- 4 cvt+4 shr
//     instead of 24 bit-twiddle ops.
// Accumulation order and weight products preserved -> bitwise-same output.

#define C_ 32
#define HW_ (128 * 128)
#define HQS 40                /* hbq row stride in shorts (80 B, 16B-aligned) */

typedef short s8v __attribute__((ext_vector_type(8)));
typedef float f4v __attribute__((ext_vector_type(4)));
typedef unsigned int u4v __attribute__((ext_vector_type(4)));
typedef unsigned int u2v __attribute__((ext_vector_type(2)));

__device__ __attribute__((aligned(64))) unsigned short g_planes[3 * HW_ * C_]; // (3,H,W,C) bf16
__device__ __attribute__((aligned(16))) unsigned short g_w0[128 * 32];
__device__ __attribute__((aligned(16))) unsigned short g_w1[128 * 128];
__device__ __attribute__((aligned(16))) unsigned short g_w2[16 * 128];  // perm-baked, padded
__device__ __attribute__((aligned(16))) float g_b0[128];
__device__ __attribute__((aligned(16))) float g_b1[128];
__device__ __attribute__((aligned(16))) float g_b2p[16];

template <typename TO, typename FROM>
static __device__ __forceinline__ TO bitc(FROM f) {
    union { FROM a; TO b; } u; u.a = f; return u.b;
}

// MFMA operand-type shim (v8i16 vs v8bf16 builtin signature) -- proven.
template <typename V>
static __device__ __forceinline__ auto mfma_k32(V a, V b, f4v c, int)
    -> decltype(__builtin_amdgcn_mfma_f32_16x16x32_bf16(a, b, c, 0, 0, 0)) {
    return __builtin_amdgcn_mfma_f32_16x16x32_bf16(a, b, c, 0, 0, 0);
}
template <typename V>
static __device__ __forceinline__ f4v mfma_k32(V a, V b, f4v c, long) {
    typedef __bf16 b8v __attribute__((ext_vector_type(8)));
    return __builtin_amdgcn_mfma_f32_16x16x32_bf16(bitc<b8v>(a), bitc<b8v>(b), c, 0, 0, 0);
}
static __device__ __forceinline__ f4v MFMA(s8v a, s8v b, f4v c) {
    return mfma_k32(a, b, c, 0);
}

__device__ __forceinline__ unsigned short f2bf(float f) {
    union { float f; unsigned int i; } v; v.f = f;
    unsigned int r = v.i + 0x7FFFu + ((v.i >> 16) & 1u);
    return (unsigned short)(r >> 16);
}

// relu + pack 2 floats -> 1 u32 of 2 bf16 via v_cvt_pk_bf16_f32 (no builtin
// on gfx950 -- inline asm per guide T12)
static __device__ __forceinline__ unsigned int relu_pk(float a, float b) {
    float x = a > 0.0f ? a : 0.0f;
    float y = b > 0.0f ? b : 0.0f;
    unsigned int r;
    asm("v_cvt_pk_bf16_f32 %0, %1, %2" : "=v"(r) : "v"(x), "v"(y));
    return r;
}
static __device__ __forceinline__ unsigned int cvt_pk(float a, float b) {
    unsigned int r;
    asm("v_cvt_pk_bf16_f32 %0, %1, %2" : "=v"(r) : "v"(a), "v"(b));
    return r;
}

// ---- prep: planes (3C,H,W) fp32 -> (3,H,W,C) bf16, LDS tile transpose ------
__global__ __launch_bounds__(256) void prep_planes_k(const float* __restrict__ tp) {
    __shared__ float buf[32][65];
    const int tid = threadIdx.x;
    const int bid = blockIdx.x;          // 0..767
    const int pl  = bid >> 8;            // plane 0..2
    const int xy0 = (bid & 255) << 6;    // 64-texel chunk
#pragma unroll
    for (int i = 0; i < 8; ++i) {
        int idx = i * 256 + tid;
        int c = idx >> 6, x = idx & 63;                       // coalesced read
        buf[c][x] = tp[(pl * C_ + c) * HW_ + xy0 + x];
    }
    __syncthreads();
#pragma unroll
    for (int i = 0; i < 8; ++i) {
        int idx = i * 256 + tid;
        int x = idx >> 5, c = idx & 31;                       // coalesced write
        g_planes[(pl * HW_ + xy0 + x) * C_ + c] = f2bf(buf[c][x]);
    }
}

// ---- prep: weights/biases -> bf16; w2/b2 permuted [1,2,3,0], padded ---------
__global__ void prep_weights_k(const float* __restrict__ w0, const float* __restrict__ b0,
                               const float* __restrict__ w1, const float* __restrict__ b1,
                               const float* __restrict__ w2, const float* __restrict__ b2) {
    int i = blockIdx.x * 256 + threadIdx.x;   // 16384 threads
    if (i < 128 * 32)  g_w0[i] = f2bf(w0[i]);
    if (i < 128 * 128) g_w1[i] = f2bf(w1[i]);
    if (i < 16 * 128) {
        int n = i >> 7, k = i & 127;
        g_w2[i] = f2bf(n < 4 ? w2[((n + 1) & 3) * 128 + k] : 0.0f);
    }
    if (i < 128) { g_b0[i] = b0[i]; g_b1[i] = b1[i]; }
    if (i < 16)  g_b2p[i] = (i < 4) ? b2[(i + 1) & 3] : 0.0f;
}

// ---- clamp-free bilinear helpers -------------------------------------------
// 8 channels (one 16B quarter) accumulate: facc[j] += w * corner[j]
static __device__ __forceinline__ void corner8(const unsigned short* __restrict__ rp,
                                               float w, float* facc) {
    const u4v dw = *(const u4v*)rp;
#pragma unroll
    for (int jj = 0; jj < 4; ++jj) {
        facc[2 * jj]     += w * __uint_as_float(dw[jj] << 16);
        facc[2 * jj + 1] += w * __uint_as_float(dw[jj] & 0xFFFF0000u);
    }
}
// one plane, 4 corners; ia indexes W (fast, stride C_), ib indexes H
static __device__ __forceinline__ void plane8(const unsigned short* __restrict__ pb,
                                              int ia, int ib, float wa, float wb,
                                              float* facc) {
    const unsigned short* r0 = pb + (ib * 128 + ia) * C_;
    const unsigned short* r1 = r0 + 128 * C_;
    const float wa0 = 1.0f - wa, wb0 = 1.0f - wb;
    corner8(r0,      wa0 * wb0, facc);   // (b0,a0)  -- same order as reference
    corner8(r0 + C_, wa  * wb0, facc);   // (b0,a1)
    corner8(r1,      wa0 * wb,  facc);   // (b1,a0)
    corner8(r1 + C_, wa  * wb,  facc);   // (b1,a1)
}

// ---- fused kernel -----------------------------------------------------------
__global__ __launch_bounds__(256) void fused_k(const float* __restrict__ coords,
                                               float* __restrict__ out) {
    // S[32][512] bf16 (32768 B) + 4 per-wave chunk bufs 16*HQS shorts (5120 B)
    // + bias table (1024 B) = 38912 B.
    __shared__ __attribute__((aligned(16))) unsigned short smem[16384 + 4 * 16 * HQS];
    __shared__ __attribute__((aligned(16))) float lds_bias[256];   // b0[128], b1[128]
    const int tid  = threadIdx.x;             // 0..255
    const int wave = tid >> 6;                // 0..3
    const int lane = tid & 63;
    const int l15  = lane & 15;
    const int quad = lane >> 4;
    const int ch8  = quad * 8;

    const int wg = blockIdx.x;                // 0..2047
    const int b  = wg >> 9;                   // batch
    const int nb = wg & 511;                  // 512-point block within batch
    const int n0 = nb << 9;

    if (tid < 128) { lds_bias[tid] = g_b0[tid]; lds_bias[128 + tid] = g_b1[tid]; }

    // ---- phase A: coalesced gather remap (lane = point*4 + quarter) --------
    {
        const int qa  = lane & 3;             // channel quarter 0..3
        const int p15 = lane >> 2;            // point-within-group 0..15
        const unsigned short* pb0 = g_planes + 0 * (HW_ * C_) + qa * 8;
        const unsigned short* pb1 = g_planes + 1 * (HW_ * C_) + qa * 8;
        const unsigned short* pb2 = g_planes + 2 * (HW_ * C_) + qa * 8;
#pragma unroll 1
        for (int s = 0; s < 8; ++s) {
            const int nl = s * 64 + wave * 16 + p15;   // 0..511
            const float* cp = coords + (size_t)(b * 262144 + n0 + nl) * 3;
            const float gx = cp[0], gy = cp[1], gz = cp[2];

            // per-AXIS math, once (clamp-free: base index <=126; inputs in [-1,1])
            float fx = (gx + 1.0f) * 63.5f;
            float fy = (gy + 1.0f) * 63.5f;
            float fz = (gz + 1.0f) * 63.5f;
            float xf = fminf(floorf(fx), 126.0f);
            float yf = fminf(floorf(fy), 126.0f);
            float zf = fminf(floorf(fz), 126.0f);
            const float wx = fx - xf, wy = fy - yf, wz = fz - zf;
            const int xi = (int)xf, yi = (int)yf, zi = (int)zf;

            float facc[8];
#pragma unroll
            for (int j = 0; j < 8; ++j) facc[j] = 0.0f;
            plane8(pb0, xi, yi, wx, wy, facc);   // feat_xy (u=x->W, v=y->H)
            plane8(pb2, xi, zi, wx, wz, facc);   // feat_xz
            plane8(pb1, yi, zi, wy, wz, facc);   // feat_yz

            // XOR swizzle keeps writes conflict-free (32 banks across lanes)
            const int nlx = nl ^ (qa << 4);
#pragma unroll
            for (int j = 0; j < 4; ++j) {
                const unsigned int p = cvt_pk(facc[2 * j], facc[2 * j + 1]);
                smem[(qa * 8 + 2 * j) * 512 + nlx]     = (unsigned short)p;
                smem[(qa * 8 + 2 * j + 1) * 512 + nlx] = (unsigned short)(p >> 16);
            }
        }
    }
    __syncthreads();

    // ---- weight fragments (identical content to proven kernel) --------------
    s8v w0f[8], w1f[4][8], w2f[4];
#pragma unroll
    for (int nt = 0; nt < 8; ++nt)
        w0f[nt] = *(const s8v*)(g_w0 + (nt * 16 + l15) * 32 + ch8);
#pragma unroll
    for (int kc = 0; kc < 4; ++kc)
#pragma unroll
        for (int nt = 0; nt < 8; ++nt)
            w1f[kc][nt] = *(const s8v*)(g_w1 + (nt * 16 + l15) * 128 + kc * 32 + ch8);
#pragma unroll
    for (int kc = 0; kc < 4; ++kc)
        w2f[kc] = *(const s8v*)(g_w2 + l15 * 128 + kc * 32 + ch8);
    const f4v b2v = *(const f4v*)(g_b2p + quad * 4);   // swapped C-init, layer 3

    unsigned short* hbq = smem + 16384 + wave * (16 * HQS);  // per-wave private
    const int xw = wave << 4;                 // read-side un-swizzle (ci>>3==wave)

    // ---- phase B: 8 tiles per wave, operand-swapped, 32-ch chunked staging --
#pragma unroll 1
    for (int i = 0; i < 8; ++i) {
        const int ci = wave * 8 + i;          // tile 0..31
        int bo = 0;
        asm volatile("" : "+v"(bo));          // opaque 0: keep bias reads in-loop
        const float* bp = lds_bias + bo;

        const s8v a = *(const s8v*)(smem + ci * 512 + ((l15 * 32 + ch8) ^ xw));

        // layer-2 accumulators, bias-initialized up front
        f4v d[8];
#pragma unroll
        for (int j = 0; j < 8; ++j)
            d[j] = *(const f4v*)(bp + 128 + j * 16 + quad * 4);

        // layer 1 -> layer 2, one 32-ch chunk (= 2 nt) at a time through hbq
#pragma unroll
        for (int kc = 0; kc < 4; ++kc) {
#pragma unroll
            for (int s = 0; s < 2; ++s) {
                const int nt = 2 * kc + s;
                const f4v bi = *(const f4v*)(bp + nt * 16 + quad * 4);
                f4v c1 = MFMA(w0f[nt], a, bi);
                u2v pk;
                pk[0] = relu_pk(c1[0], c1[1]);
                pk[1] = relu_pk(c1[2], c1[3]);
                // bytes: l15*80 + s*32 + quad*8  (8B-aligned, conflict-free)
                *(u2v*)(hbq + l15 * HQS + s * 16 + quad * 4) = pk;
            }
            const s8v a2 = *(const s8v*)(hbq + l15 * HQS + ch8);  // 16B-aligned
#pragma unroll
            for (int j = 0; j < 8; ++j)
                d[j] = MFMA(w1f[kc][j], a2, d[j]);
        }

        // layer 2 -> layer 3, same chunking (kc ascending, same accum order)
        f4v o = b2v;
#pragma unroll
        for (int kc = 0; kc < 4; ++kc) {
#pragma unroll
            for (int s = 0; s < 2; ++s) {
                const int j = 2 * kc + s;
                u2v pk;
                pk[0] = relu_pk(d[j][0], d[j][1]);
                pk[1] = relu_pk(d[j][2], d[j][3]);
                *(u2v*)(hbq + l15 * HQS + s * 16 + quad * 4) = pk;
            }
            const s8v a3 = *(const s8v*)(hbq + l15 * HQS + ch8);
            o = MFMA(w2f[kc], a3, o);
        }

        // layer 3 result: quad0 lane l15 holds comps 0..3 of its point
        if (quad == 0) {
            f4v r;
#pragma unroll
            for (int j = 0; j < 4; ++j) r[j] = o[j] > 0.0f ? o[j] : 0.0f;
            const int t = b * 16384 + ci * 512 + nb;   // global tile index
            *(f4v*)(out + (size_t)(t * 16 + l15) * 4) = r;
        }
    }
}

extern "C" void kernel_launch(void* const* d_in, const int* in_sizes, int n_in,
                              void* d_out, int out_size, void* d_ws, size_t ws_size,
                              hipStream_t stream) {
    const float* coords = (const float*)d_in[0];
    const float* tp = (const float*)d_in[1];
    const float* w0 = (const float*)d_in[2];
    const float* b0 = (const float*)d_in[3];
    const float* w1 = (const float*)d_in[4];
    const float* b1 = (const float*)d_in[5];
    const float* w2 = (const float*)d_in[6];
    const float* b2 = (const float*)d_in[7];
    float* out = (float*)d_out;               // FP32 output

    prep_planes_k<<<768, 256, 0, stream>>>(tp);
    prep_weights_k<<<64, 256, 0, stream>>>(w0, b0, w1, b1, w2, b2);
    fused_k<<<2048, 256, 0, stream>>>(coords, out);
}